// Round 1
// 334.167 us; speedup vs baseline: 1.0366x; 1.0366x over previous
//
#include <hip/hip_runtime.h>

#define NN 50000
#define NPAD 50048   // rows padded to multiple of 64 for MFMA tiles
#define NE 800000
#define FIN 64
#define H 128
#define NG 16
#define POOL_BLOCKS 1000
#define POOL_NODES 50
#define NPART 64         // private pooled-accumulator copies (atomic spreading)
#define NBUCK 196        // buckets of 256 dst nodes
#define BUCK_CAP 4800    // edges per bucket capacity (expected 4096 +- 64)
#define FILLA_BLOCKS 512
#define FILLA_CHUNK 1563  // ceil(NE / FILLA_BLOCKS)
#define CHUNK_U 16       // uints per node per feature-chunk (32 feats)
#define DUMMY NN         // zero pad row used for CSR padding
#define AGG_CH (NPAD / 64) // 782 blocks per chunk (64 nodes/block)
#define ZERO_I4 33024    // int4s to zero: poolpart+pcntpart = 132096 ints
#define PREP_ITEMS (NPAD * FIN + H * FIN + 3 * H * H + ZERO_I4)
#define PREP_BLOCKS ((PREP_ITEMS + 255) / 256)

typedef __bf16 bf16x8 __attribute__((ext_vector_type(8)));
typedef float f32x4 __attribute__((ext_vector_type(4)));
typedef float f32x2 __attribute__((ext_vector_type(2)));

// ---- helpers ----
__device__ inline unsigned short bf16r(float x) {
    unsigned int u = __float_as_uint(x);
    return (unsigned short)((u + 0x7fffu + ((u >> 16) & 1u)) >> 16);
}
__device__ inline unsigned int pack_bf16x2(float a, float b) {
    return (unsigned int)bf16r(a) | ((unsigned int)bf16r(b) << 16);
}
__device__ inline float bf_lo(unsigned int u) { return __uint_as_float(u << 16); }
__device__ inline float bf_hi(unsigned int u) { return __uint_as_float(u & 0xffff0000u); }

// packed fp32 add: acc(pair) += {lo(u), hi(u)} — 3 VALU per uint instead of 4
__device__ inline void pkadd(f32x2& a, unsigned int u) {
    f32x2 p;
    p.x = bf_lo(u);
    p.y = bf_hi(u);
    asm("v_pk_add_f32 %0, %1, %0" : "+v"(a) : "v"(p));
}

// ====== fillA + prep merged: blocks [0,512) bucket edges; rest convert x/W + zero pool ======
__global__ __launch_bounds__(256) void fillA_prep_kernel(const int* __restrict__ ei,
                                                         int* __restrict__ gcount,
                                                         unsigned int* __restrict__ ebuf,
                                                         const float* __restrict__ x,
                                                         const float* __restrict__ W1,
                                                         const float* __restrict__ W2,
                                                         const float* __restrict__ W3,
                                                         const float* __restrict__ W4,
                                                         unsigned short* __restrict__ xb,
                                                         unsigned short* __restrict__ Wt1,
                                                         unsigned short* __restrict__ Wt2,
                                                         unsigned short* __restrict__ Wt3,
                                                         unsigned short* __restrict__ Wt4,
                                                         int4* __restrict__ zbuf) {
    const int t = threadIdx.x;
    if (blockIdx.x >= FILLA_BLOCKS) {
        // ---- prep part ----
        int e = (blockIdx.x - FILLA_BLOCKS) * 256 + t;
        if (e < NPAD * FIN) {
            int n = e >> 6, k = e & 63;
            unsigned short v = (n < NN) ? bf16r(x[n * FIN + k]) : (unsigned short)0;
            xb[(size_t)(k >> 5) * (NPAD * 32) + n * 32 + (k & 31)] = v;
            return;
        }
        int tt = e - NPAD * FIN;
        if (tt < H * FIN) {
            int n = tt / FIN, k = tt % FIN;
            Wt1[tt] = bf16r(W1[k * H + n]);
            return;
        }
        int u = tt - H * FIN;
        if (u < 3 * H * H) {
            const float* W = W2;
            unsigned short* Wt = Wt2;
            if (u >= 2 * H * H) { W = W4; Wt = Wt4; u -= 2 * H * H; }
            else if (u >= H * H) { W = W3; Wt = Wt3; u -= H * H; }
            int n = u / H, k = u % H;
            Wt[u] = bf16r(W[k * H + n]);
            return;
        }
        int z = u - 3 * H * H;
        if (z < ZERO_I4) zbuf[z] = make_int4(0, 0, 0, 0);  // zero pool partials
        return;
    }
    // ---- fillA part: histogram into 196 buckets of 256 nodes ----
    __shared__ int hist[256];
    __shared__ int base[256];
    hist[t] = 0;
    __syncthreads();
    const int e0 = blockIdx.x * FILLA_CHUNK;
    const int e1 = min(e0 + FILLA_CHUNK, NE);
    for (int e = e0 + t; e < e1; e += 256)
        atomicAdd(&hist[ei[NE + e] >> 8], 1);
    __syncthreads();
    {
        int h = hist[t];
        base[t] = h ? atomicAdd(&gcount[t], h) : 0;
    }
    __syncthreads();
    for (int e = e0 + t; e < e1; e += 256) {
        int d = ei[NE + e];
        int s = ei[e];
        int b = d >> 8;
        int pos = atomicAdd(&base[b], 1);
        ebuf[b * BUCK_CAP + pos] = (unsigned int)s | ((unsigned int)d << 16);
    }
}

// fillB (fused hist+scan+scatter), 196 blocks, 1 node per thread:
// LDS hist -> pad8 counts -> scan -> one global atomicAdd reserves csr window ->
// rowse (start,end) + dinv + LDS-cursor scatter + DUMMY pads.
__global__ __launch_bounds__(256) void fillB_kernel(const unsigned int* __restrict__ ebuf,
                                                    const int* __restrict__ gcount,
                                                    int* __restrict__ galloc,
                                                    int2* __restrict__ rowse,
                                                    float* __restrict__ dinv,
                                                    unsigned short* __restrict__ csr) {
    __shared__ int lh[256];
    __shared__ int lsum[256];
    __shared__ int lcur[256];
    __shared__ int base_s;
    const int b = blockIdx.x, t = threadIdx.x;
    const int n0 = b * 256;
    lh[t] = 0;
    __syncthreads();
    const int ne = gcount[b];
    const unsigned int* __restrict__ eb = ebuf + b * BUCK_CAP;
    for (int i = t; i < ne; i += 256)
        atomicAdd(&lh[(int)(eb[i] >> 16) - n0], 1);
    __syncthreads();
    const int c = lh[t];
    const int p = (c + 7) & ~7;
    lsum[t] = p;
    __syncthreads();
    for (int off = 1; off < 256; off <<= 1) {
        int u = (t >= off) ? lsum[t - off] : 0;
        __syncthreads();
        lsum[t] += u;
        __syncthreads();
    }
    if (t == 255) base_s = atomicAdd(galloc, lsum[255]);
    const int excl = t ? lsum[t - 1] : 0;
    __syncthreads();
    const int st = base_s + excl;
    const int n = n0 + t;
    if (n < NN) {
        rowse[n] = make_int2(st, st + p);
        dinv[n] = rsqrtf((float)c + 1.0f);  // +1 self-loop
    } else if (n < NPAD) {
        rowse[n] = make_int2(0, 0);
        dinv[n] = 0.0f;
    }
    lcur[t] = st;
    __syncthreads();
    for (int i = t; i < ne; i += 256) {
        unsigned int u = eb[i];
        int pos = atomicAdd(&lcur[(int)(u >> 16) - n0], 1);
        csr[pos] = (unsigned short)(u & 0xFFFFu);
    }
    __syncthreads();
    for (int k = st + c; k < st + p; k++) csr[k] = (unsigned short)DUMMY;
}

// ===== MFMA GEMM (chunked in/out): hw' = (h @ W) * dinv[row], bf16 out =====
#define LSTRIDE 130
template <int K>
__global__ __launch_bounds__(256) void gemm_mfma_kernel(const unsigned short* __restrict__ hb,
                                                        const unsigned short* __restrict__ Wt,
                                                        const float* __restrict__ dinv,
                                                        unsigned int* __restrict__ outu) {
    __shared__ float ls[64 * LSTRIDE];  // ~33 KB
    const int wave = threadIdx.x >> 6, lane = threadIdx.x & 63;
    const int m15 = lane & 15, quad = lane >> 4;
    const int row0 = blockIdx.x * 64;
    const int arow = row0 + wave * 16 + m15;

    bf16x8 a[K / 32];
#pragma unroll
    for (int ks = 0; ks < K / 32; ks++)
        a[ks] = *(const bf16x8*)&hb[(size_t)ks * (NPAD * 32) + arow * 32 + quad * 8];

    const int lrow = wave * 16 + quad * 4;
    float dv[4];
#pragma unroll
    for (int r = 0; r < 4; r++) dv[r] = dinv[row0 + lrow + r];

#pragma unroll
    for (int ct = 0; ct < 8; ct++) {
        f32x4 acc = {0.f, 0.f, 0.f, 0.f};
#pragma unroll
        for (int ks = 0; ks < K / 32; ks++) {
            bf16x8 b = *(const bf16x8*)&Wt[(ct * 16 + m15) * K + ks * 32 + quad * 8];
            acc = __builtin_amdgcn_mfma_f32_16x16x32_bf16(a[ks], b, acc, 0, 0, 0);
        }
#pragma unroll
        for (int r = 0; r < 4; r++)
            ls[(lrow + r) * LSTRIDE + ct * 16 + m15] = acc[r] * dv[r];
    }
    __syncthreads();

#pragma unroll
    for (int k = 0; k < 4; k++) {
        int idx = threadIdx.x + 256 * k;
        int c = idx >> 8, row = (idx >> 2) & 63, q = idx & 3;
        const float* p = &ls[row * LSTRIDE + c * 32 + q * 8];
        uint4 o;
        o.x = pack_bf16x2(p[0], p[1]);
        o.y = pack_bf16x2(p[2], p[3]);
        o.z = pack_bf16x2(p[4], p[5]);
        o.w = pack_bf16x2(p[6], p[7]);
        *(uint4*)&outu[(size_t)c * (NPAD * CHUNK_U) + (size_t)(row0 + row) * CHUNK_U + q * 4] = o;
    }
}

// ====== feature-chunked gather aggregation ======
// 4 lanes per node, each lane owns 4 uints (uint4 = 16B gathers),
// v_pk_add_f32 accumulation: ~2x fewer VALU + 4x fewer load instrs per slot.
template <bool RELU_BIAS>
__global__ __launch_bounds__(256) void agg_kernel(const unsigned int* __restrict__ hwc,
                                                  const int2* __restrict__ rowse,
                                                  const unsigned short* __restrict__ csr,
                                                  const float* __restrict__ dinv,
                                                  const float* __restrict__ bias,
                                                  unsigned int* __restrict__ outc) {
    const int chunk = blockIdx.x / AGG_CH;
    const int nb = blockIdx.x % AGG_CH;
    const int g = threadIdx.x & 3;            // lane's uint-quad within the chunk
    const int n = nb * 64 + (threadIdx.x >> 2);  // node (64 per block, incl. pad rows)
    const int u0 = g * 4;
    const unsigned int* __restrict__ slice = hwc + (size_t)chunk * (NPAD * CHUNK_U);

    uint4 sv = *(const uint4*)&slice[n * CHUNK_U + u0];  // self-loop term
    f32x2 a0 = {bf_lo(sv.x), bf_hi(sv.x)};
    f32x2 a1 = {bf_lo(sv.y), bf_hi(sv.y)};
    f32x2 a2 = {bf_lo(sv.z), bf_hi(sv.z)};
    f32x2 a3 = {bf_lo(sv.w), bf_hi(sv.w)};

    const int2 se = rowse[n];  // start/end, both multiples of 8
    for (int i = se.x; i < se.y; i += 8) {
        uint4 c = *(const uint4*)&csr[i];  // 8 ushort srcs
        int s0 = c.x & 0xFFFF, s1 = c.x >> 16;
        int s2 = c.y & 0xFFFF, s3 = c.y >> 16;
        int s4 = c.z & 0xFFFF, s5 = c.z >> 16;
        int s6 = c.w & 0xFFFF, s7 = c.w >> 16;
        uint4 v0 = *(const uint4*)&slice[s0 * CHUNK_U + u0];
        uint4 v1 = *(const uint4*)&slice[s1 * CHUNK_U + u0];
        uint4 v2 = *(const uint4*)&slice[s2 * CHUNK_U + u0];
        uint4 v3 = *(const uint4*)&slice[s3 * CHUNK_U + u0];
        uint4 v4 = *(const uint4*)&slice[s4 * CHUNK_U + u0];
        uint4 v5 = *(const uint4*)&slice[s5 * CHUNK_U + u0];
        uint4 v6 = *(const uint4*)&slice[s6 * CHUNK_U + u0];
        uint4 v7 = *(const uint4*)&slice[s7 * CHUNK_U + u0];
        pkadd(a0, v0.x); pkadd(a1, v0.y); pkadd(a2, v0.z); pkadd(a3, v0.w);
        pkadd(a0, v1.x); pkadd(a1, v1.y); pkadd(a2, v1.z); pkadd(a3, v1.w);
        pkadd(a0, v2.x); pkadd(a1, v2.y); pkadd(a2, v2.z); pkadd(a3, v2.w);
        pkadd(a0, v3.x); pkadd(a1, v3.y); pkadd(a2, v3.z); pkadd(a3, v3.w);
        pkadd(a0, v4.x); pkadd(a1, v4.y); pkadd(a2, v4.z); pkadd(a3, v4.w);
        pkadd(a0, v5.x); pkadd(a1, v5.y); pkadd(a2, v5.z); pkadd(a3, v5.w);
        pkadd(a0, v6.x); pkadd(a1, v6.y); pkadd(a2, v6.z); pkadd(a3, v6.w);
        pkadd(a0, v7.x); pkadd(a1, v7.y); pkadd(a2, v7.z); pkadd(a3, v7.w);
    }

    const float d = dinv[n];
    uint4 o;
    if (RELU_BIAS) {
        const float2* bp = (const float2*)bias + chunk * CHUNK_U + u0;
        float2 q0 = bp[0], q1 = bp[1], q2 = bp[2], q3 = bp[3];
        o.x = pack_bf16x2(fmaxf(a0.x * d + q0.x, 0.f), fmaxf(a0.y * d + q0.y, 0.f));
        o.y = pack_bf16x2(fmaxf(a1.x * d + q1.x, 0.f), fmaxf(a1.y * d + q1.y, 0.f));
        o.z = pack_bf16x2(fmaxf(a2.x * d + q2.x, 0.f), fmaxf(a2.y * d + q2.y, 0.f));
        o.w = pack_bf16x2(fmaxf(a3.x * d + q3.x, 0.f), fmaxf(a3.y * d + q3.y, 0.f));
    } else {
        o.x = pack_bf16x2(a0.x * d, a0.y * d);
        o.y = pack_bf16x2(a1.x * d, a1.y * d);
        o.z = pack_bf16x2(a2.x * d, a2.y * d);
        o.w = pack_bf16x2(a3.x * d, a3.y * d);
    }
    *(uint4*)&outc[(size_t)chunk * (NPAD * CHUNK_U) + (size_t)n * CHUNK_U + u0] = o;
}

// ======== pooling: 1000 blocks x 50 nodes; atomics spread over NPART copies ========
__global__ __launch_bounds__(256) void pool_kernel(const unsigned int* __restrict__ hbu,
                                                   const float* __restrict__ b4,
                                                   const int* __restrict__ batch,
                                                   float* __restrict__ poolpart,
                                                   float* __restrict__ pcntpart) {
    __shared__ int bs[POOL_NODES];
    const int tid = threadIdx.x;
    const int n0 = blockIdx.x * POOL_NODES;
    if (tid < POOL_NODES) bs[tid] = batch[n0 + tid];
    __syncthreads();
    float* __restrict__ pooled = poolpart + (blockIdx.x & (NPART - 1)) * (NG * H);
    float* __restrict__ cnt = pcntpart + (blockIdx.x & (NPART - 1)) * NG;
    const int c2 = tid & 63;                 // feature-uint index 0..63
    const int chunk = c2 >> 4, u = c2 & 15;
    const int rsub = tid >> 6;  // 0..3
    float2 bb = ((const float2*)b4)[c2];
    float2 acc = {0.f, 0.f};
    float cacc = 0.f;
    int curg = bs[rsub];
    const size_t coff = (size_t)chunk * (NPAD * CHUNK_U) + u;
    for (int r = rsub; r < POOL_NODES; r += 4) {
        int g = bs[r];
        if (g != curg) {
            atomicAdd(&pooled[curg * H + c2 * 2], acc.x);
            atomicAdd(&pooled[curg * H + c2 * 2 + 1], acc.y);
            if (c2 == 0) atomicAdd(&cnt[curg], cacc);
            acc.x = acc.y = 0.f;
            cacc = 0.f;
            curg = g;
        }
        unsigned int v = hbu[coff + (size_t)(n0 + r) * CHUNK_U];
        acc.x += bf_lo(v) + bb.x;
        acc.y += bf_hi(v) + bb.y;
        cacc += 1.f;
    }
    atomicAdd(&pooled[curg * H + c2 * 2], acc.x);
    atomicAdd(&pooled[curg * H + c2 * 2 + 1], acc.y);
    if (c2 == 0) atomicAdd(&cnt[curg], cacc);
}

// ============ final MLP (single block): reduce NPART copies, then GEMMs ============
__global__ __launch_bounds__(1024) void mlp_kernel(const float* __restrict__ poolpart,
                                                   const float* __restrict__ pcntpart,
                                                   const float* __restrict__ lw1,
                                                   const float* __restrict__ lb1,
                                                   const float* __restrict__ lw2,
                                                   const float* __restrict__ lb2,
                                                   float* __restrict__ out) {
    __shared__ float mean_s[NG * H];
    __shared__ float cnt_s[NG];
    __shared__ float hid_s[NG * 64];
    int tid = threadIdx.x;
    if (tid < NG) {
        float c = 0.f;
        for (int p = 0; p < NPART; p++) c += pcntpart[p * NG + tid];
        cnt_s[tid] = fmaxf(c, 1.0f);
    }
    __syncthreads();
    for (int i = tid; i < NG * H; i += 1024) {
        float s = 0.f;
        for (int p = 0; p < NPART; p++) s += poolpart[p * (NG * H) + i];
        mean_s[i] = s / cnt_s[i >> 7];
    }
    __syncthreads();
    {
        int g = tid >> 6, j = tid & 63;
        float acc = lb1[j];
        for (int f = 0; f < H; f++) acc += mean_s[g * H + f] * lw1[f * 64 + j];
        hid_s[g * 64 + j] = fmaxf(acc, 0.f);
    }
    __syncthreads();
    if (tid < 32) {
        int g = tid >> 1, c = tid & 1;
        float acc = lb2[c];
        for (int j = 0; j < 64; j++) acc += hid_s[g * 64 + j] * lw2[j * 2 + c];
        out[g * 2 + c] = acc;
    }
}

extern "C" void kernel_launch(void* const* d_in, const int* in_sizes, int n_in,
                              void* d_out, int out_size, void* d_ws, size_t ws_size,
                              hipStream_t stream) {
    const float* x = (const float*)d_in[0];
    const int* ei = (const int*)d_in[1];
    const int* batch = (const int*)d_in[2];
    const float* W1 = (const float*)d_in[3];
    const float* b1 = (const float*)d_in[4];
    const float* W2 = (const float*)d_in[5];
    const float* b2 = (const float*)d_in[6];
    const float* W3 = (const float*)d_in[7];
    const float* b3 = (const float*)d_in[8];
    const float* W4 = (const float*)d_in[9];
    const float* b4 = (const float*)d_in[10];
    const float* lw1 = (const float*)d_in[11];
    const float* lb1 = (const float*)d_in[12];
    const float* lw2 = (const float*)d_in[13];
    const float* lb2 = (const float*)d_in[14];
    float* out = (float*)d_out;

    // workspace layout (4-byte units; sizes annotated in ints); ~39.5 MB
    int* wsi = (int*)d_ws;
    int* gcount = wsi;                                      // @0        256
    int* galloc = wsi + 256;                                // @256      1 (pad to 512)
    float* poolpart = (float*)(wsi + 512);                  // @512      131072 (NPART*NG*H)
    float* pcntpart = (float*)(wsi + 131584);               // @131584   1024 (NPART*NG)
    int2* rowse = (int2*)(wsi + 132608);                    // @132608   100096 (NPAD int2)
    unsigned short* csr = (unsigned short*)(wsi + 232704);  // @232704   600000 (1.2M ushorts)
    float* dinv = (float*)(wsi + 832704);                   // @832704   50048
    unsigned short* Wt1 = (unsigned short*)(wsi + 882752);  // @882752   4096 (8192 shorts)
    unsigned short* Wt2 = (unsigned short*)(wsi + 886848);  // @886848   8192 (16384 shorts)
    unsigned short* Wt3 = (unsigned short*)(wsi + 895040);  // @895040   8192
    unsigned short* Wt4 = (unsigned short*)(wsi + 903232);  // @903232   8192
    unsigned short* xb = (unsigned short*)(wsi + 911424);   // @911424   1601536 (NPAD*64 shorts)
    unsigned int* hb = (unsigned int*)(wsi + 2512960);      // @2512960  3203072 (NPAD*64 uints)
    unsigned int* hwb = (unsigned int*)(wsi + 5716032);     // @5716032  3203072
    unsigned int* ebuf = (unsigned int*)(wsi + 8919104);    // @8919104  940800 -> ends 9859904

    const int gemmBlocks = NPAD / 64;          // 782
    const int aggBlocks = 4 * AGG_CH;          // 3128, chunk-major

    // ---- zero control vars (tiny); pool partials zeroed inside prep ----
    hipMemsetAsync(wsi, 0, 512 * sizeof(int), stream);
    fillA_prep_kernel<<<FILLA_BLOCKS + PREP_BLOCKS, 256, 0, stream>>>(
        ei, gcount, ebuf, x, W1, W2, W3, W4, xb, Wt1, Wt2, Wt3, Wt4, (int4*)poolpart);
    fillB_kernel<<<NBUCK, 256, 0, stream>>>(ebuf, gcount, galloc, rowse, dinv, csr);

    // ---- layer 1 ----
    gemm_mfma_kernel<FIN><<<gemmBlocks, 256, 0, stream>>>(xb, Wt1, dinv, hwb);
    agg_kernel<true><<<aggBlocks, 256, 0, stream>>>(hwb, rowse, csr, dinv, b1, hb);
    // ---- layer 2 ----
    gemm_mfma_kernel<H><<<gemmBlocks, 256, 0, stream>>>((unsigned short*)hb, Wt2, dinv, hwb);
    agg_kernel<true><<<aggBlocks, 256, 0, stream>>>(hwb, rowse, csr, dinv, b2, hb);
    // ---- layer 3 ----
    gemm_mfma_kernel<H><<<gemmBlocks, 256, 0, stream>>>((unsigned short*)hb, Wt3, dinv, hwb);
    agg_kernel<true><<<aggBlocks, 256, 0, stream>>>(hwb, rowse, csr, dinv, b3, hb);
    // ---- layer 4 (no relu/bias; b4 fused in pool) ----
    gemm_mfma_kernel<H><<<gemmBlocks, 256, 0, stream>>>((unsigned short*)hb, Wt4, dinv, hwb);
    agg_kernel<false><<<aggBlocks, 256, 0, stream>>>(hwb, rowse, csr, dinv, nullptr, hb);

    // ---- pooling (fused +b4, partials zeroed in prep) + MLP ----
    pool_kernel<<<POOL_BLOCKS, 256, 0, stream>>>(hb, b4, batch, poolpart, pcntpart);
    mlp_kernel<<<1, 1024, 0, stream>>>(poolpart, pcntpart, lw1, lb1, lw2, lb2, out);
}